// Round 10
// baseline (314.544 us; speedup 1.0000x reference)
//
#include <hip/hip_runtime.h>

#define N_N 50000
#define N_E 800000
#define NG  128
#define NBKT 782          // ceil(50000/64) buckets of 64 nodes
#define CAP  1536         // slot capacity per bucket (mean 1023, sigma 32)
#define EPB  8192         // edges per k_bin block
#define BINB 98           // ceil(800000/8192)
#define AGG_BLKS 12500    // node-blocks per chunk (4 nodes/block)

typedef float4 f4;
typedef __attribute__((ext_vector_type(8))) short bf16x8;
typedef __attribute__((ext_vector_type(4))) float f32x4;

__device__ __forceinline__ unsigned short f2b(float x){
  unsigned int u = __float_as_uint(x);
  u += 0x7fffu + ((u >> 16) & 1u);
  return (unsigned short)(u >> 16);
}
__device__ __forceinline__ float b2f(unsigned short h){
  return __uint_as_float(((unsigned int)h) << 16);
}
__device__ __forceinline__ float2 b2f2(unsigned int u){
  float2 r;
  r.x = __uint_as_float(u << 16);
  r.y = __uint_as_float(u & 0xffff0000u);
  return r;
}

// ---------------- init: Wt transpose-cast (blocks 0..127) + zero counters (blocks 128+) ----------------
__global__ __launch_bounds__(256) void k_init(const float* __restrict__ W1, const float* __restrict__ W2,
    unsigned short* __restrict__ Wt1, unsigned short* __restrict__ Wt2,
    int* __restrict__ zp, int n4){
  int i = blockIdx.x*256 + threadIdx.x;
  if (blockIdx.x < 128){
    const float* W = (i < 16384) ? W1 : W2;
    unsigned short* Wt = (i < 16384) ? Wt1 : Wt2;
    int j = i & 16383;
    int k = j >> 7, n = j & 127;
    Wt[n*128 + k] = f2b(W[k*128 + n]);
  } else {
    int z = i - 128*256;
    if (z < n4) zp[z] = 0;
  }
}

// ---------------- block-local counting sort into coarse buckets ----------------
// packs (src<<16 | dst) into u32 (both < 65536)
__global__ __launch_bounds__(512) void k_bin(const int* __restrict__ ei,
    int* __restrict__ bcnt, unsigned int* __restrict__ bins){
  __shared__ unsigned int sorted[EPB];   // 32 KB
  __shared__ int hist[NBKT];
  __shared__ int lstart[NBKT];
  __shared__ int lcur[NBKT];
  __shared__ int gbase[NBKT];
  __shared__ int segsum[16];
  int t = threadIdx.x;
  int e0 = blockIdx.x * EPB;
  int n = N_E - e0; if (n > EPB) n = EPB;
  for (int i=t; i<NBKT; i+=512) hist[i] = 0;
  __syncthreads();
  for (int i=t; i<n; i+=512){
    int d = ei[N_E + e0 + i];
    atomicAdd(&hist[d>>6], 1);
  }
  __syncthreads();
  int w = t >> 6, lane = t & 63;
  for (int seg = w; seg < 13; seg += 8){
    int idx = seg*64 + lane;
    int v = (idx < NBKT) ? hist[idx] : 0;
    int x = v;
    #pragma unroll
    for (int dd=1; dd<64; dd<<=1){ int y = __shfl_up(x, dd, 64); if (lane >= dd) x += y; }
    if (idx < NBKT) lstart[idx] = x - v;
    if (lane == 63) segsum[seg] = x;
  }
  __syncthreads();
  if (t == 0){ int s=0; for (int j=0;j<13;j++){ int v=segsum[j]; segsum[j]=s; s+=v; } }
  __syncthreads();
  for (int i=t; i<NBKT; i+=512){ int v = lstart[i] + segsum[i>>6]; lstart[i] = v; lcur[i] = v; }
  __syncthreads();
  for (int i=t; i<n; i+=512){
    int s = ei[e0 + i], d = ei[N_E + e0 + i];
    int pos = atomicAdd(&lcur[d>>6], 1);
    sorted[pos] = ((unsigned int)s << 16) | (unsigned int)d;
  }
  __syncthreads();
  for (int i=t; i<NBKT; i+=512) gbase[i] = atomicAdd(&bcnt[i], hist[i]);
  __syncthreads();
  for (int i=t; i<n; i+=512){
    unsigned int item = sorted[i];
    int d = item & 0xffff;
    int b = d >> 6;
    bins[b*CAP + gbase[b] + (i - lstart[b])] = item;
  }
}

// ---------------- fused: per-bucket CSR finalize + preprocess MLP (same 782-block grid) ----------------
__global__ __launch_bounds__(256) void k_csrpre(const unsigned int* __restrict__ bins,
    const int* __restrict__ bcnt, int2* __restrict__ sd, float* __restrict__ dinv,
    int* __restrict__ ssrc,
    const float* __restrict__ emb, const float* __restrict__ pose,
    const float* __restrict__ W, const float* __restrict__ bias, unsigned short* __restrict__ out){
  __shared__ float As[64*64];
  __shared__ float Bs[64*128];
  __shared__ int hist[64];
  __shared__ int lcur[64];
  __shared__ int cnt_s;
  int b = blockIdx.x, t = threadIdx.x;

  // ---- CSR phase ----
  if (t < 64) hist[t] = 0;
  if (t == 0) cnt_s = bcnt[b];
  __syncthreads();
  int cnt = cnt_s;
  const unsigned int* P = bins + b*CAP;
  for (int j=t; j<cnt; j+=256) atomicAdd(&hist[P[j] & 63], 1);
  __syncthreads();
  if (t < 64){
    int v = hist[t];
    int x = v;
    #pragma unroll
    for (int dd=1; dd<64; dd<<=1){ int y = __shfl_up(x, dd, 64); if (t >= dd) x += y; }
    int excl = x - v;
    int node = (b<<6) + t;
    if (node < N_N){
      sd[node] = make_int2(b*CAP + excl, v);
      dinv[node] = rsqrtf((float)(v + 1));    // +1 self-loop
    }
    lcur[t] = b*CAP + excl;
  }
  __syncthreads();
  for (int j=t; j<cnt; j+=256){
    unsigned int p = P[j];
    int pos = atomicAdd(&lcur[p & 63], 1);
    ssrc[pos] = (int)(p >> 16);
  }

  // ---- preprocess MLP phase (independent data; same block count) ----
  int row0 = b*64;
  for (int j=t; j<2048; j+=256) ((f4*)Bs)[j] = ((const f4*)W)[j];
  for (int j=t; j<1024; j+=256){
    int r = j>>4, c4 = j&15;
    int gr = row0 + r;
    f4 a = {0.f,0.f,0.f,0.f};
    if (gr < N_N){
      f4 e0 = ((const f4*)emb)[gr*16 + c4];
      f4 p0 = ((const f4*)pose)[gr*16 + c4];
      a.x = e0.x+p0.x; a.y = e0.y+p0.y; a.z = e0.z+p0.z; a.w = e0.w+p0.w;
    }
    ((f4*)As)[j] = a;
  }
  __syncthreads();
  int cg = t&31, rg = t>>5;
  float acc[8][4] = {};
  for (int k=0;k<64;k++){
    f4 bb = ((f4*)Bs)[k*32 + cg];
    #pragma unroll
    for (int i=0;i<8;i++){
      float a = As[(rg*8+i)*64 + k];
      acc[i][0] = fmaf(a,bb.x,acc[i][0]); acc[i][1] = fmaf(a,bb.y,acc[i][1]);
      acc[i][2] = fmaf(a,bb.z,acc[i][2]); acc[i][3] = fmaf(a,bb.w,acc[i][3]);
    }
  }
  f4 bb = ((const f4*)bias)[cg];
  for (int i=0;i<8;i++){
    int gr = row0 + rg*8 + i;
    if (gr < N_N){
      ushort4 o;
      o.x = f2b(fmaxf(acc[i][0]+bb.x, 0.f));
      o.y = f2b(fmaxf(acc[i][1]+bb.y, 0.f));
      o.z = f2b(fmaxf(acc[i][2]+bb.z, 0.f));
      o.w = f2b(fmaxf(acc[i][3]+bb.w, 0.f));
      *(ushort4*)&out[gr*128 + cg*4] = o;
    }
  }
}

// ---------------- MFMA GEMM: hs = (A @ W) * dinv[row], A bf16 [M][128], Wt bf16 [n][k] ----------------
__global__ __launch_bounds__(256) void k_gemm_mfma(const unsigned short* __restrict__ A,
    const unsigned short* __restrict__ Wt, const float* __restrict__ scale,
    unsigned short* __restrict__ out){
  __shared__ unsigned short Bs[128*128];   // 32 KB, XOR-swizzled [n][k] tiles of 8 bf16
  int tid = threadIdx.x;
  for (int j=tid; j<2048; j+=256){
    int n = j >> 4, c = j & 15;
    ((bf16x8*)Bs)[(n<<4) | (c ^ (n&7))] = ((const bf16x8*)Wt)[j];
  }
  __syncthreads();
  int wid = tid >> 6, l = tid & 63;
  int row0 = blockIdx.x*128 + wid*32;
  int lr = l & 15, kg = l >> 4;
  int ra = row0 + lr;       if (ra > N_N-1) ra = N_N-1;
  int rb = row0 + 16 + lr;  if (rb > N_N-1) rb = N_N-1;
  f32x4 acc[2][8] = {};
  #pragma unroll
  for (int ks=0; ks<4; ks++){
    int k0 = ks*32 + kg*8;
    bf16x8 a0 = *(const bf16x8*)&A[ra*128 + k0];
    bf16x8 a1 = *(const bf16x8*)&A[rb*128 + k0];
    #pragma unroll
    for (int nf=0; nf<8; nf++){
      int n = nf*16 + lr;
      bf16x8 b = ((const bf16x8*)Bs)[(n<<4) | ((ks*4+kg) ^ (lr&7))];
      acc[0][nf] = __builtin_amdgcn_mfma_f32_16x16x32_bf16(a0, b, acc[0][nf], 0, 0, 0);
      acc[1][nf] = __builtin_amdgcn_mfma_f32_16x16x32_bf16(a1, b, acc[1][nf], 0, 0, 0);
    }
  }
  #pragma unroll
  for (int mf=0; mf<2; mf++){
    #pragma unroll
    for (int r=0; r<4; r++){
      int R = row0 + mf*16 + (l>>4)*4 + r;
      if (R < N_N){
        float s = scale[R];
        #pragma unroll
        for (int nf=0; nf<8; nf++){
          out[R*128 + nf*16 + lr] = f2b(acc[mf][nf][r] * s);
        }
      }
    }
  }
}

// ---------------- L2-chunked edge aggregation, row-major table ----------------
// grid = 4*AGG_BLKS, chunk = bid/AGG_BLKS: each pass gathers one 64B line per row (3.2MB working set, L2-fits)
// wave = 1 node; 4 x 16-lane groups each process a different edge per step (4 lines/instr);
// unroll 4 per group -> 16 gathers + 16 index loads in flight per wave.
__global__ __launch_bounds__(256) void k_agg4(const unsigned int* __restrict__ hs,  // [N_N][64] dwords
    const int2* __restrict__ sd, const int* __restrict__ ssrc, const float* __restrict__ dinv,
    const float* __restrict__ bias, unsigned int* __restrict__ out){
  int bid = blockIdx.x;
  int chunk = bid / AGG_BLKS;
  int nb = bid - chunk*AGG_BLKS;
  int wid = threadIdx.x >> 6, l = threadIdx.x & 63;
  int v = nb*4 + wid;
  int g = l >> 4, f = l & 15;
  int base = chunk*16 + f;              // dword index within 64-dword row
  int2 s_d = sd[v];
  int s = s_d.x, cnt = s_d.y;
  float2 acc = {0.f, 0.f};
  int k = g;
  for (; k + 12 < cnt; k += 16){
    int u0 = __builtin_nontemporal_load(ssrc + s + k);
    int u1 = __builtin_nontemporal_load(ssrc + s + k + 4);
    int u2 = __builtin_nontemporal_load(ssrc + s + k + 8);
    int u3 = __builtin_nontemporal_load(ssrc + s + k + 12);
    unsigned int m0 = hs[u0*64 + base];
    unsigned int m1 = hs[u1*64 + base];
    unsigned int m2 = hs[u2*64 + base];
    unsigned int m3 = hs[u3*64 + base];
    float2 f0 = b2f2(m0), f1 = b2f2(m1), f2 = b2f2(m2), f3 = b2f2(m3);
    acc.x += (f0.x + f1.x) + (f2.x + f3.x);
    acc.y += (f0.y + f1.y) + (f2.y + f3.y);
  }
  for (; k < cnt; k += 4){
    int u = __builtin_nontemporal_load(ssrc + s + k);
    float2 m = b2f2(hs[u*64 + base]);
    acc.x += m.x; acc.y += m.y;
  }
  // combine the 4 groups (butterfly leaves sum in all lanes)
  acc.x += __shfl_xor(acc.x, 16, 64); acc.y += __shfl_xor(acc.y, 16, 64);
  acc.x += __shfl_xor(acc.x, 32, 64); acc.y += __shfl_xor(acc.y, 32, 64);
  // self-loop + scale + bias + relu
  float2 sf = b2f2(hs[v*64 + base]);
  acc.x += sf.x; acc.y += sf.y;
  float dv = dinv[v];
  float2 bb = ((const float2*)bias)[base];
  unsigned int o = (unsigned int)f2b(fmaxf(fmaf(dv, acc.x, bb.x), 0.f))
                 | ((unsigned int)f2b(fmaxf(fmaf(dv, acc.y, bb.y), 0.f)) << 16);
  if (g == 0) out[v*64 + base] = o;
}

// ---------------- mean pool over sorted batch (bf16 row-major in) ----------------
__global__ __launch_bounds__(128) void k_pool(const unsigned short* __restrict__ x, const int* __restrict__ batch,
    float* __restrict__ gsum, float* __restrict__ gcnt){
  int c = threadIdx.x;
  int n0 = blockIdx.x*128;
  int n1 = n0 + 128; if (n1 > N_N) n1 = N_N;
  int cur = batch[n0];
  float acc = 0.f, cnt = 0.f;
  for (int i=n0; i<n1; i++){
    int b = batch[i];
    if (b != cur){
      atomicAdd(&gsum[cur*128+c], acc);
      if (c == 0) atomicAdd(&gcnt[cur], cnt);
      acc = 0.f; cnt = 0.f; cur = b;
    }
    acc += b2f(x[i*128+c]);
    cnt += 1.f;
  }
  atomicAdd(&gsum[cur*128+c], acc);
  if (c == 0) atomicAdd(&gcnt[cur], cnt);
}

// ---------------- head MLP (128->64->32, relu both) ----------------
__global__ __launch_bounds__(64) void k_head(const float* __restrict__ gsum, const float* __restrict__ gcnt,
    const float* __restrict__ W1, const float* __restrict__ b1,
    const float* __restrict__ W2, const float* __restrict__ b2, float* __restrict__ out){
  __shared__ float pooled[128];
  __shared__ float h1[64];
  int g = blockIdx.x, t = threadIdx.x;
  float cnt = fmaxf(gcnt[g], 1.f);
  pooled[t]      = gsum[g*128 + t] / cnt;
  pooled[t + 64] = gsum[g*128 + 64 + t] / cnt;
  __syncthreads();
  float a = b1[t];
  for (int k=0; k<128; k++) a = fmaf(pooled[k], W1[k*64 + t], a);
  h1[t] = fmaxf(a, 0.f);
  __syncthreads();
  if (t < 32){
    float o = b2[t];
    for (int k=0; k<64; k++) o = fmaf(h1[k], W2[k*32 + t], o);
    out[g*32 + t] = fmaxf(o, 0.f);
  }
}

extern "C" void kernel_launch(void* const* d_in, const int* in_sizes, int n_in,
                              void* d_out, int out_size, void* d_ws, size_t ws_size,
                              hipStream_t stream){
  const float* emb  = (const float*)d_in[0];
  const float* pose = (const float*)d_in[1];
  const int*   ei   = (const int*)d_in[2];
  const int*   batch= (const int*)d_in[3];
  const float* Wpre = (const float*)d_in[4];
  const float* bpre = (const float*)d_in[5];
  const float* Wg1  = (const float*)d_in[6];
  const float* bg1  = (const float*)d_in[7];
  const float* Wg2  = (const float*)d_in[8];
  const float* bg2  = (const float*)d_in[9];
  const float* Wh1  = (const float*)d_in[10];
  const float* bh1  = (const float*)d_in[11];
  const float* Wh2  = (const float*)d_in[12];
  const float* bh2  = (const float*)d_in[13];
  float* out = (float*)d_out;

  char* ws = (char*)d_ws;
  unsigned short* xb0 = (unsigned short*)(ws + 0);          // 12,800,000 (row-major [N_N][128])
  unsigned short* xb1 = (unsigned short*)(ws + 12800000);   // 12,800,000
  unsigned short* hb  = (unsigned short*)(ws + 25600000);   // 12,800,000
  unsigned short* Wt1 = (unsigned short*)(ws + 38400000);   // 32,768
  unsigned short* Wt2 = (unsigned short*)(ws + 38432768);   // 32,768
  int2*  sd   = (int2*) (ws + 38465536);   // 400,000
  float* dinv = (float*)(ws + 38865536);   // 200,000
  int*   ssrc = (int*)  (ws + 39065536);   // NBKT*CAP*4 = 4,804,608
  unsigned int* bins = (unsigned int*)(ws + 43870144);   // NBKT*CAP*4 = 4,804,608
  // contiguous zero region: bcnt | gsum | gcnt
  int*   bcnt = (int*)  (ws + 48674752);   // NBKT*4 = 3,128 (pad to 3,136)
  float* gsum = (float*)(ws + 48677888);   // 65,536
  float* gcnt = (float*)(ws + 48743424);   // 512

  const int ZN = (3136 + 65536 + 512) / 4;   // 17,296 ints
  const int ZB = (ZN + 255)/256;             // 68 blocks

  k_init<<<128 + ZB, 256, 0, stream>>>(Wg1, Wg2, Wt1, Wt2, bcnt, ZN);

  k_bin<<<BINB, 512, 0, stream>>>(ei, bcnt, bins);
  k_csrpre<<<NBKT, 256, 0, stream>>>(bins, bcnt, sd, dinv, ssrc,
                                     emb, pose, Wpre, bpre, xb0);                 // CSR + x1 -> xb0

  k_gemm_mfma<<<(N_N+127)/128, 256, 0, stream>>>(xb0, Wt1, dinv, hb);             // hs1 -> hb
  k_agg4<<<4*AGG_BLKS, 256, 0, stream>>>((const unsigned int*)hb, sd, ssrc, dinv, bg1, (unsigned int*)xb1);

  k_gemm_mfma<<<(N_N+127)/128, 256, 0, stream>>>(xb1, Wt2, dinv, hb);             // hs2 -> hb
  k_agg4<<<4*AGG_BLKS, 256, 0, stream>>>((const unsigned int*)hb, sd, ssrc, dinv, bg2, (unsigned int*)xb0);

  k_pool<<<(N_N+127)/128, 128, 0, stream>>>(xb0, batch, gsum, gcnt);
  k_head<<<NG, 64, 0, stream>>>(gsum, gcnt, Wh1, bh1, Wh2, bh2, out);
}

// Round 11
// 180.456 us; speedup vs baseline: 1.7431x; 1.7431x over previous
//
#include <hip/hip_runtime.h>

#define N_N 50000
#define N_E 800000
#define NG  128
#define NBKT 782          // ceil(50000/64) buckets of 64 nodes
#define CAP  1536         // slot capacity per bucket (padded mean 1248, sigma ~37 -> 7.8 sigma margin)
#define EPB  8192         // edges per k_bin block
#define BINB 98           // ceil(800000/8192)

typedef float4 f4;
typedef __attribute__((ext_vector_type(8))) short bf16x8;
typedef __attribute__((ext_vector_type(4))) float f32x4;

__device__ __forceinline__ unsigned short f2b(float x){
  unsigned int u = __float_as_uint(x);
  u += 0x7fffu + ((u >> 16) & 1u);
  return (unsigned short)(u >> 16);
}
__device__ __forceinline__ float b2f(unsigned short h){
  return __uint_as_float(((unsigned int)h) << 16);
}
__device__ __forceinline__ float2 b2f2(unsigned int u){
  float2 r;
  r.x = __uint_as_float(u << 16);
  r.y = __uint_as_float(u & 0xffff0000u);
  return r;
}

// ---------------- init: Wt transpose-cast + zero counters + zero sentinel row of hb ----------------
__global__ __launch_bounds__(256) void k_init(const float* __restrict__ W1, const float* __restrict__ W2,
    unsigned short* __restrict__ Wt1, unsigned short* __restrict__ Wt2,
    int* __restrict__ zp, int n4, unsigned int* __restrict__ hbz){
  int bid = blockIdx.x, t = threadIdx.x;
  int i = bid*256 + t;
  if (bid < 128){
    const float* W = (i < 16384) ? W1 : W2;
    unsigned short* Wt = (i < 16384) ? Wt1 : Wt2;
    int j = i & 16383;
    int k = j >> 7, n = j & 127;
    Wt[n*128 + k] = f2b(W[k*128 + n]);
  } else if (bid == gridDim.x - 1){
    if (t < 64) hbz[(size_t)N_N*64 + t] = 0;   // sentinel row (padding gathers land here)
  } else {
    int z = i - 128*256;
    if (z < n4) zp[z] = 0;
  }
}

// ---------------- block-local counting sort into coarse buckets ----------------
// packs (src<<16 | dst) into u32 (both < 65536)
__global__ __launch_bounds__(512) void k_bin(const int* __restrict__ ei,
    int* __restrict__ bcnt, unsigned int* __restrict__ bins){
  __shared__ unsigned int sorted[EPB];   // 32 KB
  __shared__ int hist[NBKT];
  __shared__ int lstart[NBKT];
  __shared__ int lcur[NBKT];
  __shared__ int gbase[NBKT];
  __shared__ int segsum[16];
  int t = threadIdx.x;
  int e0 = blockIdx.x * EPB;
  int n = N_E - e0; if (n > EPB) n = EPB;
  for (int i=t; i<NBKT; i+=512) hist[i] = 0;
  __syncthreads();
  for (int i=t; i<n; i+=512){
    int d = ei[N_E + e0 + i];
    atomicAdd(&hist[d>>6], 1);
  }
  __syncthreads();
  int w = t >> 6, lane = t & 63;
  for (int seg = w; seg < 13; seg += 8){
    int idx = seg*64 + lane;
    int v = (idx < NBKT) ? hist[idx] : 0;
    int x = v;
    #pragma unroll
    for (int dd=1; dd<64; dd<<=1){ int y = __shfl_up(x, dd, 64); if (lane >= dd) x += y; }
    if (idx < NBKT) lstart[idx] = x - v;
    if (lane == 63) segsum[seg] = x;
  }
  __syncthreads();
  if (t == 0){ int s=0; for (int j=0;j<13;j++){ int v=segsum[j]; segsum[j]=s; s+=v; } }
  __syncthreads();
  for (int i=t; i<NBKT; i+=512){ int v = lstart[i] + segsum[i>>6]; lstart[i] = v; lcur[i] = v; }
  __syncthreads();
  for (int i=t; i<n; i+=512){
    int s = ei[e0 + i], d = ei[N_E + e0 + i];
    int pos = atomicAdd(&lcur[d>>6], 1);
    sorted[pos] = ((unsigned int)s << 16) | (unsigned int)d;
  }
  __syncthreads();
  for (int i=t; i<NBKT; i+=512) gbase[i] = atomicAdd(&bcnt[i], hist[i]);
  __syncthreads();
  for (int i=t; i<n; i+=512){
    unsigned int item = sorted[i];
    int d = item & 0xffff;
    int b = d >> 6;
    bins[b*CAP + gbase[b] + (i - lstart[b])] = item;
  }
}

// ---------------- fused: per-bucket CSR finalize (8-padded segments) + preprocess MLP ----------------
__global__ __launch_bounds__(256) void k_csrpre(const unsigned int* __restrict__ bins,
    const int* __restrict__ bcnt, int2* __restrict__ sd, float* __restrict__ dinv,
    int* __restrict__ ssrc,
    const float* __restrict__ emb, const float* __restrict__ pose,
    const float* __restrict__ W, const float* __restrict__ bias, unsigned short* __restrict__ out){
  __shared__ float As[64*64];
  __shared__ float Bs[64*128];
  __shared__ int hist[64];
  __shared__ int lcur[64];
  __shared__ int cnt_s;
  int b = blockIdx.x, t = threadIdx.x;

  // ---- CSR phase ----
  if (t < 64) hist[t] = 0;
  if (t == 0) cnt_s = bcnt[b];
  __syncthreads();
  int cnt = cnt_s;
  const unsigned int* P = bins + b*CAP;
  for (int j=t; j<cnt; j+=256) atomicAdd(&hist[P[j] & 63], 1);
  __syncthreads();
  if (t < 64){
    int v = hist[t];
    int ph = (v + 7) & ~7;               // padded to multiple of 8
    int x = ph;
    #pragma unroll
    for (int dd=1; dd<64; dd<<=1){ int y = __shfl_up(x, dd, 64); if (t >= dd) x += y; }
    int excl = x - ph;
    int node = (b<<6) + t;
    if (node < N_N){
      sd[node] = make_int2(b*CAP + excl, ph);          // padded count
      dinv[node] = rsqrtf((float)(v + 1));             // real count +1 self-loop
    }
    lcur[t] = b*CAP + excl;
    // sentinel-fill the pad slots
    for (int j=v; j<ph; j++) ssrc[b*CAP + excl + j] = N_N;
  }
  __syncthreads();
  for (int j=t; j<cnt; j+=256){
    unsigned int p = P[j];
    int pos = atomicAdd(&lcur[p & 63], 1);
    ssrc[pos] = (int)(p >> 16);
  }

  // ---- preprocess MLP phase (independent data; same block count) ----
  int row0 = b*64;
  for (int j=t; j<2048; j+=256) ((f4*)Bs)[j] = ((const f4*)W)[j];
  for (int j=t; j<1024; j+=256){
    int r = j>>4, c4 = j&15;
    int gr = row0 + r;
    f4 a = {0.f,0.f,0.f,0.f};
    if (gr < N_N){
      f4 e0 = ((const f4*)emb)[gr*16 + c4];
      f4 p0 = ((const f4*)pose)[gr*16 + c4];
      a.x = e0.x+p0.x; a.y = e0.y+p0.y; a.z = e0.z+p0.z; a.w = e0.w+p0.w;
    }
    ((f4*)As)[j] = a;
  }
  __syncthreads();
  int cg = t&31, rg = t>>5;
  float acc[8][4] = {};
  for (int k=0;k<64;k++){
    f4 bb = ((f4*)Bs)[k*32 + cg];
    #pragma unroll
    for (int i=0;i<8;i++){
      float a = As[(rg*8+i)*64 + k];
      acc[i][0] = fmaf(a,bb.x,acc[i][0]); acc[i][1] = fmaf(a,bb.y,acc[i][1]);
      acc[i][2] = fmaf(a,bb.z,acc[i][2]); acc[i][3] = fmaf(a,bb.w,acc[i][3]);
    }
  }
  f4 bb = ((const f4*)bias)[cg];
  for (int i=0;i<8;i++){
    int gr = row0 + rg*8 + i;
    if (gr < N_N){
      ushort4 o;
      o.x = f2b(fmaxf(acc[i][0]+bb.x, 0.f));
      o.y = f2b(fmaxf(acc[i][1]+bb.y, 0.f));
      o.z = f2b(fmaxf(acc[i][2]+bb.z, 0.f));
      o.w = f2b(fmaxf(acc[i][3]+bb.w, 0.f));
      *(ushort4*)&out[gr*128 + cg*4] = o;
    }
  }
}

// ---------------- MFMA GEMM: hs = (A @ W) * dinv[row], A bf16 [M][128], Wt bf16 [n][k] ----------------
__global__ __launch_bounds__(256) void k_gemm_mfma(const unsigned short* __restrict__ A,
    const unsigned short* __restrict__ Wt, const float* __restrict__ scale,
    unsigned short* __restrict__ out){
  __shared__ unsigned short Bs[128*128];   // 32 KB, XOR-swizzled [n][k] tiles of 8 bf16
  int tid = threadIdx.x;
  for (int j=tid; j<2048; j+=256){
    int n = j >> 4, c = j & 15;
    ((bf16x8*)Bs)[(n<<4) | (c ^ (n&7))] = ((const bf16x8*)Wt)[j];
  }
  __syncthreads();
  int wid = tid >> 6, l = tid & 63;
  int row0 = blockIdx.x*128 + wid*32;
  int lr = l & 15, kg = l >> 4;
  int ra = row0 + lr;       if (ra > N_N-1) ra = N_N-1;
  int rb = row0 + 16 + lr;  if (rb > N_N-1) rb = N_N-1;
  f32x4 acc[2][8] = {};
  #pragma unroll
  for (int ks=0; ks<4; ks++){
    int k0 = ks*32 + kg*8;
    bf16x8 a0 = *(const bf16x8*)&A[ra*128 + k0];
    bf16x8 a1 = *(const bf16x8*)&A[rb*128 + k0];
    #pragma unroll
    for (int nf=0; nf<8; nf++){
      int n = nf*16 + lr;
      bf16x8 b = ((const bf16x8*)Bs)[(n<<4) | ((ks*4+kg) ^ (lr&7))];
      acc[0][nf] = __builtin_amdgcn_mfma_f32_16x16x32_bf16(a0, b, acc[0][nf], 0, 0, 0);
      acc[1][nf] = __builtin_amdgcn_mfma_f32_16x16x32_bf16(a1, b, acc[1][nf], 0, 0, 0);
    }
  }
  #pragma unroll
  for (int mf=0; mf<2; mf++){
    #pragma unroll
    for (int r=0; r<4; r++){
      int R = row0 + mf*16 + (l>>4)*4 + r;
      if (R < N_N){
        float s = scale[R];
        #pragma unroll
        for (int nf=0; nf<8; nf++){
          out[R*128 + nf*16 + lr] = f2b(acc[mf][nf][r] * s);
        }
      }
    }
  }
}

// ---------------- edge aggregation: out[v] = relu(dinv[v]*(hs[v] + sum hs[src]) + b), bf16 ----------------
// padded CSR: count multiple of 8, sentinel src = N_N (zero row). No tail loop.
__global__ __launch_bounds__(256) void k_agg(const unsigned int* __restrict__ h2,  // [N_N+1][64] dwords
    const int2* __restrict__ sd, const int* __restrict__ ssrc, const float* __restrict__ dinv,
    const float* __restrict__ bias, unsigned int* __restrict__ out){
  int v = blockIdx.x*4 + (threadIdx.x>>6);
  int l = threadIdx.x & 63;
  float2 acc = b2f2(h2[(v<<6) + l]);                  // self-loop term hs[v]
  int2 s_d = sd[v];
  int s = s_d.x, pc = s_d.y;                          // 16B-aligned start, padded count
  for (int k=0; k<pc; k+=8){
    int4 ua = *(const int4*)(ssrc + s + k);
    int4 ub = *(const int4*)(ssrc + s + k + 4);
    unsigned int m0 = h2[(ua.x<<6)+l], m1 = h2[(ua.y<<6)+l];
    unsigned int m2 = h2[(ua.z<<6)+l], m3 = h2[(ua.w<<6)+l];
    unsigned int m4 = h2[(ub.x<<6)+l], m5 = h2[(ub.y<<6)+l];
    unsigned int m6 = h2[(ub.z<<6)+l], m7 = h2[(ub.w<<6)+l];
    float2 f0=b2f2(m0), f1=b2f2(m1), f2=b2f2(m2), f3=b2f2(m3);
    float2 f4_=b2f2(m4), f5=b2f2(m5), f6=b2f2(m6), f7=b2f2(m7);
    acc.x += ((f0.x+f1.x)+(f2.x+f3.x)) + ((f4_.x+f5.x)+(f6.x+f7.x));
    acc.y += ((f0.y+f1.y)+(f2.y+f3.y)) + ((f4_.y+f5.y)+(f6.y+f7.y));
  }
  float dv = dinv[v];
  float2 bb = ((const float2*)bias)[l];
  unsigned int o = (unsigned int)f2b(fmaxf(fmaf(dv, acc.x, bb.x), 0.f))
                 | ((unsigned int)f2b(fmaxf(fmaf(dv, acc.y, bb.y), 0.f)) << 16);
  out[(v<<6) + l] = o;
}

// ---------------- mean pool over sorted batch (bf16 row-major in) ----------------
__global__ __launch_bounds__(128) void k_pool(const unsigned short* __restrict__ x, const int* __restrict__ batch,
    float* __restrict__ gsum, float* __restrict__ gcnt){
  int c = threadIdx.x;
  int n0 = blockIdx.x*128;
  int n1 = n0 + 128; if (n1 > N_N) n1 = N_N;
  int cur = batch[n0];
  float acc = 0.f, cnt = 0.f;
  for (int i=n0; i<n1; i++){
    int b = batch[i];
    if (b != cur){
      atomicAdd(&gsum[cur*128+c], acc);
      if (c == 0) atomicAdd(&gcnt[cur], cnt);
      acc = 0.f; cnt = 0.f; cur = b;
    }
    acc += b2f(x[i*128+c]);
    cnt += 1.f;
  }
  atomicAdd(&gsum[cur*128+c], acc);
  if (c == 0) atomicAdd(&gcnt[cur], cnt);
}

// ---------------- head MLP (128->64->32, relu both) ----------------
__global__ __launch_bounds__(64) void k_head(const float* __restrict__ gsum, const float* __restrict__ gcnt,
    const float* __restrict__ W1, const float* __restrict__ b1,
    const float* __restrict__ W2, const float* __restrict__ b2, float* __restrict__ out){
  __shared__ float pooled[128];
  __shared__ float h1[64];
  int g = blockIdx.x, t = threadIdx.x;
  float cnt = fmaxf(gcnt[g], 1.f);
  pooled[t]      = gsum[g*128 + t] / cnt;
  pooled[t + 64] = gsum[g*128 + 64 + t] / cnt;
  __syncthreads();
  float a = b1[t];
  for (int k=0; k<128; k++) a = fmaf(pooled[k], W1[k*64 + t], a);
  h1[t] = fmaxf(a, 0.f);
  __syncthreads();
  if (t < 32){
    float o = b2[t];
    for (int k=0; k<64; k++) o = fmaf(h1[k], W2[k*32 + t], o);
    out[g*32 + t] = fmaxf(o, 0.f);
  }
}

extern "C" void kernel_launch(void* const* d_in, const int* in_sizes, int n_in,
                              void* d_out, int out_size, void* d_ws, size_t ws_size,
                              hipStream_t stream){
  const float* emb  = (const float*)d_in[0];
  const float* pose = (const float*)d_in[1];
  const int*   ei   = (const int*)d_in[2];
  const int*   batch= (const int*)d_in[3];
  const float* Wpre = (const float*)d_in[4];
  const float* bpre = (const float*)d_in[5];
  const float* Wg1  = (const float*)d_in[6];
  const float* bg1  = (const float*)d_in[7];
  const float* Wg2  = (const float*)d_in[8];
  const float* bg2  = (const float*)d_in[9];
  const float* Wh1  = (const float*)d_in[10];
  const float* bh1  = (const float*)d_in[11];
  const float* Wh2  = (const float*)d_in[12];
  const float* bh2  = (const float*)d_in[13];
  float* out = (float*)d_out;

  char* ws = (char*)d_ws;
  unsigned short* xb0 = (unsigned short*)(ws + 0);          // 12,800,000 (row-major [N_N][128])
  unsigned short* xb1 = (unsigned short*)(ws + 12800000);   // 12,800,000
  unsigned short* hb  = (unsigned short*)(ws + 25600000);   // 12,800,256 ((N_N+1) rows: +sentinel)
  unsigned short* Wt1 = (unsigned short*)(ws + 38400512);   // 32,768
  unsigned short* Wt2 = (unsigned short*)(ws + 38433280);   // 32,768
  int2*  sd   = (int2*) (ws + 38466048);   // 400,000
  float* dinv = (float*)(ws + 38866048);   // 200,000
  int*   ssrc = (int*)  (ws + 39066048);   // NBKT*CAP*4 = 4,804,608
  unsigned int* bins = (unsigned int*)(ws + 43870656);   // NBKT*CAP*4 = 4,804,608
  // contiguous zero region: bcnt | gsum | gcnt
  int*   bcnt = (int*)  (ws + 48675264);   // NBKT*4 = 3,128 (pad to 3,136)
  float* gsum = (float*)(ws + 48678400);   // 65,536
  float* gcnt = (float*)(ws + 48743936);   // 512

  const int ZN = (3136 + 65536 + 512) / 4;   // 17,296 ints
  const int ZB = (ZN + 255)/256;             // 68 blocks

  k_init<<<128 + ZB + 1, 256, 0, stream>>>(Wg1, Wg2, Wt1, Wt2, bcnt, ZN, (unsigned int*)hb);

  k_bin<<<BINB, 512, 0, stream>>>(ei, bcnt, bins);
  k_csrpre<<<NBKT, 256, 0, stream>>>(bins, bcnt, sd, dinv, ssrc,
                                     emb, pose, Wpre, bpre, xb0);                 // CSR + x1 -> xb0

  k_gemm_mfma<<<(N_N+127)/128, 256, 0, stream>>>(xb0, Wt1, dinv, hb);             // hs1 -> hb
  k_agg<<<N_N/4, 256, 0, stream>>>((const unsigned int*)hb, sd, ssrc, dinv, bg1, (unsigned int*)xb1);

  k_gemm_mfma<<<(N_N+127)/128, 256, 0, stream>>>(xb1, Wt2, dinv, hb);             // hs2 -> hb
  k_agg<<<N_N/4, 256, 0, stream>>>((const unsigned int*)hb, sd, ssrc, dinv, bg2, (unsigned int*)xb0);

  k_pool<<<(N_N+127)/128, 128, 0, stream>>>(xb0, batch, gsum, gcnt);
  k_head<<<NG, 64, 0, stream>>>(gsum, gcnt, Wh1, bh1, Wh2, bh2, out);
}